// Round 2
// baseline (1578.865 us; speedup 1.0000x reference)
//
#include <hip/hip_runtime.h>

typedef __attribute__((ext_vector_type(8))) short short8;
typedef __attribute__((ext_vector_type(4))) float floatx4;

#define BM 128
#define BN 128
#define BK 32

__device__ __forceinline__ float b2f(ushort us) {
    union { unsigned u; float f; } v; v.u = ((unsigned)us) << 16; return v.f;
}
__device__ __forceinline__ ushort f2b(float f) {
    union { float f; unsigned u; } v; v.f = f;
    unsigned r = (v.u + 0x7fffu + ((v.u >> 16) & 1u)) >> 16;
    return (ushort)r;
}
__device__ __forceinline__ float ldany(const void* p, long i, int bf) {
    return bf ? b2f(((const ushort*)p)[i]) : ((const float*)p)[i];
}
__device__ __forceinline__ void async16(const ushort* g, ushort* l) {
    __builtin_amdgcn_global_load_lds((const __attribute__((address_space(1))) void*)g,
                                     (__attribute__((address_space(3))) void*)l,
                                     16, 0, 0);
}

// ---------------------------------------------------------------------------
// dtype detector: low-ushort exponent field of fp32 words is uniform random;
// of bf16 elements of N(0,~0.02) weights it concentrates in [112,128].
// ---------------------------------------------------------------------------
__global__ void detect_dtype(const unsigned* __restrict__ w, int* __restrict__ flag)
{
    if (threadIdx.x == 0 && blockIdx.x == 0) {
        int votes = 0;
        for (int i = 0; i < 256; i++) {
            unsigned e = (w[i] >> 7) & 0xFFu;   // bf16 exponent of low half
            if (e >= 112u && e <= 128u) votes++;
        }
        *flag = (votes >= 128) ? 1 : 0;          // 1 = buffers are bf16
    }
}

// ---------------------------------------------------------------------------
// Transpose [R][C] (fp32 or bf16) -> bf16 [C][R]
// ---------------------------------------------------------------------------
__global__ __launch_bounds__(256) void transpose_any(
    const void* __restrict__ in, long in_off, ushort* __restrict__ out,
    int R, int C, const int* __restrict__ flag)
{
    __shared__ float tile[64][65];
    const int bf = *flag;
    const int t  = threadIdx.x;
    const long r0 = (long)blockIdx.y * 64;
    const long c0 = (long)blockIdx.x * 64;
    const int rl = t >> 4;
    const int cl = (t & 15) * 4;
    #pragma unroll
    for (int p = 0; p < 4; p++) {
        const int r = rl + p * 16;
        const long base = in_off + (r0 + r) * C + c0 + cl;
        if (bf) {
            ushort4 v = *(const ushort4*)((const ushort*)in + base);
            tile[r][cl + 0] = b2f(v.x); tile[r][cl + 1] = b2f(v.y);
            tile[r][cl + 2] = b2f(v.z); tile[r][cl + 3] = b2f(v.w);
        } else {
            float4 v = *(const float4*)((const float*)in + base);
            tile[r][cl + 0] = v.x; tile[r][cl + 1] = v.y;
            tile[r][cl + 2] = v.z; tile[r][cl + 3] = v.w;
        }
    }
    __syncthreads();
    #pragma unroll
    for (int p = 0; p < 4; p++) {
        const int oc = rl + p * 16;          // output row = original column
        ushort4 v;
        v.x = f2b(tile[cl + 0][oc]); v.y = f2b(tile[cl + 1][oc]);
        v.z = f2b(tile[cl + 2][oc]); v.w = f2b(tile[cl + 3][oc]);
        *(ushort4*)(out + (c0 + oc) * R + r0 + cl) = v;
    }
}

// ---------------------------------------------------------------------------
// raw (fp32 or bf16) -> bf16, 4 elements/thread
// ---------------------------------------------------------------------------
__global__ void to_bf16_any(const void* __restrict__ in, ushort* __restrict__ out,
                            long n4, const int* __restrict__ flag)
{
    const long i = (long)blockIdx.x * blockDim.x + threadIdx.x;
    if (i >= n4) return;
    const int bf = *flag;
    ushort4 o;
    if (bf) {
        o = ((const ushort4*)in)[i];
    } else {
        float4 v = ((const float4*)in)[i];
        o.x = f2b(v.x); o.y = f2b(v.y); o.z = f2b(v.z); o.w = f2b(v.w);
    }
    ((ushort4*)out)[i] = o;
}

// fp32 -> bf16 (internal, no flag), 4/thread
__global__ void f32_to_bf16_4(const float* __restrict__ in, ushort* __restrict__ out, long n4)
{
    const long i = (long)blockIdx.x * blockDim.x + threadIdx.x;
    if (i >= n4) return;
    float4 v = ((const float4*)in)[i];
    ushort4 o; o.x = f2b(v.x); o.y = f2b(v.y); o.z = f2b(v.z); o.w = f2b(v.w);
    ((ushort4*)out)[i] = o;
}

// ---------------------------------------------------------------------------
// m97-style bf16 GEMM: C[M,N] = A[M,K] * Bt[N,K]^T, fused epilogues
// ---------------------------------------------------------------------------
#define EPI_SILU   0   // out_bf16 = silu(acc + bias)
#define EPI_BIAS   1   // out_bf16 = acc + bias
#define EPI_EXPERT 2   // hacc += rowscale[m*4] * (acc + bias)
#define EPI_CTX    3   // hacc += acc + bias
#define EPI_OUT    4   // out(any) = acc + bias + resid_bf16[m*N+n]

template<int EPI>
__global__ __launch_bounds__(256, 2) void gemm_bt(
    const ushort* __restrict__ A, const ushort* __restrict__ Bt,
    int M, int N, int K,
    const void* __restrict__ bias, long bias_off,
    void* __restrict__ out, long ldo,
    float* __restrict__ hacc,
    const float* __restrict__ rowscale,
    const ushort* __restrict__ resid,
    const int* __restrict__ flag)
{
    __shared__ __align__(16) ushort As[BM * BK];
    __shared__ __align__(16) ushort Bs[BN * BK];

    const int tid  = threadIdx.x;
    const int lane = tid & 63;
    const int wv   = tid >> 6;
    const int wm   = wv & 1;
    const int wn   = wv >> 1;
    const long m0  = (long)blockIdx.y * BM;
    const long n0  = (long)blockIdx.x * BN;

    floatx4 acc[4][4] = {};

    const int sr = (lane >> 2);
    const int sk = (lane & 3) * 8;
    const ushort* Ag = A  + (m0 + wv * 32 + sr) * (long)K + sk;
    const ushort* Bg = Bt + (n0 + wv * 32 + sr) * (long)K + sk;
    ushort* Al = As + (wv * 32) * BK;
    ushort* Bl = Bs + (wv * 32) * BK;

    const int fr = lane & 15;       // m (or n) within 16-tile
    const int q  = lane >> 4;       // k-quad
    const ushort* ApL = As + (wm * 64 + fr) * BK + q * 8;
    const ushort* BpL = Bs + (wn * 64 + fr) * BK + q * 8;

    for (int k0 = 0; k0 < K; k0 += BK) {
        __syncthreads();                       // previous tile's reads done
        async16(Ag + k0,            Al);
        async16(Ag + 16L * K + k0,  Al + 16 * BK);
        async16(Bg + k0,            Bl);
        async16(Bg + 16L * K + k0,  Bl + 16 * BK);
        __syncthreads();                       // drains vmcnt -> LDS ready
        short8 af[4], bfr[4];
        #pragma unroll
        for (int i = 0; i < 4; i++) af[i]  = *(const short8*)(ApL + i * 16 * BK);
        #pragma unroll
        for (int j = 0; j < 4; j++) bfr[j] = *(const short8*)(BpL + j * 16 * BK);
        #pragma unroll
        for (int i = 0; i < 4; i++)
            #pragma unroll
            for (int j = 0; j < 4; j++)
                acc[i][j] = __builtin_amdgcn_mfma_f32_16x16x32_bf16(
                                af[i], bfr[j], acc[i][j], 0, 0, 0);
    }

    const int bf = *flag;
    // C[m][n]: m = (lane>>4)*4 + reg, n = lane&15 (m89-verified layout)
    #pragma unroll
    for (int i = 0; i < 4; i++) {
        #pragma unroll
        for (int r = 0; r < 4; r++) {
            const long m = m0 + wm * 64 + i * 16 + q * 4 + r;
            #pragma unroll
            for (int j = 0; j < 4; j++) {
                const long n = n0 + wn * 64 + j * 16 + fr;
                float v = acc[i][j][r] + ldany(bias, bias_off + n, bf);
                if (EPI == EPI_SILU) {
                    v = v / (1.f + __expf(-v));
                    ((ushort*)out)[m * ldo + n] = f2b(v);
                } else if (EPI == EPI_BIAS) {
                    ((ushort*)out)[m * ldo + n] = f2b(v);
                } else if (EPI == EPI_EXPERT) {
                    hacc[m * (long)N + n] += rowscale[m * 4] * v;
                } else if (EPI == EPI_CTX) {
                    hacc[m * (long)N + n] += v;
                } else {
                    v += b2f(resid[m * (long)N + n]);
                    if (bf) ((ushort*)out)[m * ldo + n] = f2b(v);
                    else    ((float*)out)[m * ldo + n]  = v;
                }
            }
        }
    }
}

// ---------------------------------------------------------------------------
// se gather: hA[m][2048 + j] = bf16(W_syn_emb[ids[m]][j]), j < 512
// ---------------------------------------------------------------------------
__global__ void gather_syn(const int* __restrict__ ids, const void* __restrict__ emb,
                           ushort* __restrict__ hA, const int* __restrict__ flag)
{
    const int bf = *flag;
    const long m = blockIdx.x;
    const int id = ids[m];
    const int j = threadIdx.x * 2;
    float a, b;
    if (bf) {
        ushort2 v = *(const ushort2*)((const ushort*)emb + (long)id * 512 + j);
        a = b2f(v.x); b = b2f(v.y);
    } else {
        float2 v = *(const float2*)((const float*)emb + (long)id * 512 + j);
        a = v.x; b = v.y;
    }
    ushort2 o; o.x = f2b(a); o.y = f2b(b);
    *(ushort2*)(hA + m * 2560 + 2048 + j) = o;
}

// ---------------------------------------------------------------------------
// gate + router; h3 = h2*gate in place (bf16) and into hacc (fp32)
// ---------------------------------------------------------------------------
__global__ __launch_bounds__(256) void gate_router(
    ushort* __restrict__ h2, float* __restrict__ hacc, float* __restrict__ probs,
    const void* __restrict__ Wg, const void* __restrict__ bg,
    const void* __restrict__ Wr, const void* __restrict__ br,
    const int* __restrict__ flag)
{
    const int bf = *flag;
    const long m = blockIdx.x;
    const int t = threadIdx.x;
    const int lane = t & 63;
    const int wv = t >> 6;
    ushort* row = h2 + m * 2048;

    float sg = 0.f, s0 = 0.f, s1 = 0.f, s2 = 0.f, s3 = 0.f;
    for (int k = t; k < 2048; k += 256) {
        const float h = b2f(row[k]);
        sg += h * ldany(Wg, k, bf);
        float r0v, r1v, r2v, r3v;
        if (bf) {
            ushort4 v = *(const ushort4*)((const ushort*)Wr + (long)k * 4);
            r0v = b2f(v.x); r1v = b2f(v.y); r2v = b2f(v.z); r3v = b2f(v.w);
        } else {
            float4 v = *(const float4*)((const float*)Wr + (long)k * 4);
            r0v = v.x; r1v = v.y; r2v = v.z; r3v = v.w;
        }
        s0 += h * r0v; s1 += h * r1v; s2 += h * r2v; s3 += h * r3v;
    }
    #pragma unroll
    for (int off = 32; off > 0; off >>= 1) {
        sg += __shfl_down(sg, off);
        s0 += __shfl_down(s0, off);
        s1 += __shfl_down(s1, off);
        s2 += __shfl_down(s2, off);
        s3 += __shfl_down(s3, off);
    }
    __shared__ float red[4][5];
    __shared__ float gate_bc;
    if (lane == 0) {
        red[wv][0] = sg; red[wv][1] = s0; red[wv][2] = s1;
        red[wv][3] = s2; red[wv][4] = s3;
    }
    __syncthreads();
    if (t == 0) {
        float G = red[0][0] + red[1][0] + red[2][0] + red[3][0];
        float R[4];
        #pragma unroll
        for (int e = 0; e < 4; e++)
            R[e] = red[0][1 + e] + red[1][1 + e] + red[2][1 + e] + red[3][1 + e];
        const float gate = 1.f / (1.f + __expf(-(G + ldany(bg, 0, bf))));
        float lg[4], mx = -1e30f;
        #pragma unroll
        for (int e = 0; e < 4; e++) {
            lg[e] = gate * R[e] + ldany(br, e, bf);
            mx = fmaxf(mx, lg[e]);
        }
        float p[4], s = 0.f;
        #pragma unroll
        for (int e = 0; e < 4; e++) { p[e] = __expf(lg[e] - mx); s += p[e]; }
        #pragma unroll
        for (int e = 0; e < 4; e++) probs[m * 4 + e] = p[e] / s;
        gate_bc = gate;
    }
    __syncthreads();
    const float gate = gate_bc;
    for (int k = t; k < 2048; k += 256) {
        const float v = b2f(row[k]) * gate;
        row[k] = f2b(v);
        hacc[m * 2048 + k] = v;
    }
}

// ---------------------------------------------------------------------------
// grouped conv1d (8 ch/group, k=3, pad 1) + combine: h5 = bf16(hacc + cb + pat)
// ---------------------------------------------------------------------------
__global__ __launch_bounds__(256) void conv_combine(
    const ushort* __restrict__ h4, const float* __restrict__ hacc,
    const void* __restrict__ cw, const void* __restrict__ cb,
    ushort* __restrict__ h5, const int* __restrict__ flag)
{
    const int S = 2048, D = 2048;
    const int bf = *flag;
    const int b = blockIdx.z, g = blockIdx.y;
    const int s0 = blockIdx.x * 64;
    __shared__ float tile[66 * 8];
    const int t = threadIdx.x;
    for (int idx = t; idx < 66 * 8; idx += 256) {
        const int sl = idx >> 3, i = idx & 7;
        const int s = s0 + sl - 1;
        float v = 0.f;
        if (s >= 0 && s < S) v = b2f(h4[((long)b * S + s) * D + g * 8 + i]);
        tile[idx] = v;
    }
    __syncthreads();
    const int io = t & 7;
    const int c = g * 8 + io;
    float w[3][8];
    #pragma unroll
    for (int kk = 0; kk < 3; kk++)
        #pragma unroll
        for (int ii = 0; ii < 8; ii++)
            w[kk][ii] = ldany(cw, (long)c * 24 + ii * 3 + kk, bf);
    const float bc = ldany(cb, c, bf);
    #pragma unroll
    for (int p = 0; p < 2; p++) {
        const int sl = (t >> 3) + p * 32;
        float pat = 0.f;
        #pragma unroll
        for (int kk = 0; kk < 3; kk++)
            #pragma unroll
            for (int ii = 0; ii < 8; ii++)
                pat += tile[(sl + kk) * 8 + ii] * w[kk][ii];
        const long m = (long)b * S + s0 + sl;
        h5[m * D + c] = f2b(hacc[m * D + c] + bc + pat);
    }
}

// ---------------------------------------------------------------------------
extern "C" void kernel_launch(void* const* d_in, const int* in_sizes, int n_in,
                              void* d_out, int out_size, void* d_ws, size_t ws_size,
                              hipStream_t stream)
{
    (void)in_sizes; (void)n_in; (void)out_size; (void)ws_size;
    const void* x        = d_in[0];
    const int*  syn      = (const int*)d_in[1];
    const void* W_in     = d_in[2];
    const void* b_in     = d_in[3];
    const void* W_synemb = d_in[4];
    const void* W_syn    = d_in[5];
    const void* b_syn    = d_in[6];
    const void* W_gate   = d_in[7];
    const void* b_gate   = d_in[8];
    const void* W_router = d_in[9];
    const void* b_router = d_in[10];
    const void* W_e1     = d_in[11];
    const void* b_e1     = d_in[12];
    const void* W_e2     = d_in[13];
    const void* b_e2     = d_in[14];
    const void* W_ctx    = d_in[15];
    const void* b_ctx    = d_in[16];
    const void* conv_w   = d_in[17];
    const void* conv_b   = d_in[18];
    const void* W_out    = d_in[19];
    const void* b_out    = d_in[20];

    char* ws = (char*)d_ws;
    int*    flag  = (int*)ws;                          // 256 B reserved
    ushort* WT    = (ushort*)(ws + 256);               // 16 MiB transposed weight
    ushort* xb    = (ushort*)(ws + 16777472);          // [4096][2048] bf16 x (dead after step 1; resid reads OK: see eh note)
    ushort* hA    = (ushort*)(ws + 33554688);          // [4096][2560] concat(h1,se); later h5 (ld 2048)
    ushort* eh    = (ushort*)(ws + 16777472);          // [4096][4096] overlaps xb+hA-head (live only in expert phase)
    ushort* h23   = (ushort*)(ws + 54526208);          // [4096][2048] h2 -> h3 -> h4(bf16)
    float*  probs = (float*)(ws + 71303424);           // [4096][4]
    float*  hacc  = (float*)(ws + 71368960);           // [4096][2048] fp32 accumulator; ends ~104.9 MB
    const int M = 4096;
    dim3 blk(256);

    // 0) dtype probe (re-runs every launch; ws is re-poisoned by harness)
    detect_dtype<<<dim3(1), dim3(64), 0, stream>>>((const unsigned*)W_in, flag);
    // 0b) xb = bf16(x)  [also the bf16 residual source for step 9]
    to_bf16_any<<<dim3(8192), blk, 0, stream>>>(x, xb, 2097152L, flag);

    // 1) h1 = silu(x @ W_in + b_in) -> hA[:, :2048] (ld 2560)
    transpose_any<<<dim3(32, 32), blk, 0, stream>>>(W_in, 0, WT, 2048, 2048, flag);
    gemm_bt<EPI_SILU><<<dim3(16, 32), blk, 0, stream>>>(
        xb, WT, M, 2048, 2048, b_in, 0, hA, 2560, nullptr, nullptr, nullptr, flag);
    // 2) se gather -> hA[:, 2048:2560]
    gather_syn<<<dim3(4096), blk, 0, stream>>>(syn, W_synemb, hA, flag);
    // 3) h2 = concat(h1,se) @ W_syn + b_syn -> h23
    transpose_any<<<dim3(32, 40), blk, 0, stream>>>(W_syn, 0, WT, 2560, 2048, flag);
    gemm_bt<EPI_BIAS><<<dim3(16, 32), blk, 0, stream>>>(
        hA, WT, M, 2048, 2560, b_syn, 0, h23, 2048, nullptr, nullptr, nullptr, flag);
    // 4) gate + router; h3 in place; hacc = h3
    gate_router<<<dim3(4096), blk, 0, stream>>>(
        h23, hacc, probs, W_gate, b_gate, W_router, b_router, flag);
    // 5) experts: hacc += probs_e * (silu(h3 @ We1 + b1) @ We2 + b2)
    //    NOTE: eh overlaps xb/hA storage — both dead during this phase... xb is
    //    needed again only at step 9 as residual; so re-derive it after experts.
    for (int e = 0; e < 4; e++) {
        transpose_any<<<dim3(64, 32), blk, 0, stream>>>(
            W_e1, (long)e * 8388608, WT, 2048, 4096, flag);
        gemm_bt<EPI_SILU><<<dim3(32, 32), blk, 0, stream>>>(
            h23, WT, M, 4096, 2048, b_e1, (long)e * 4096, eh, 4096,
            nullptr, nullptr, nullptr, flag);
        transpose_any<<<dim3(32, 64), blk, 0, stream>>>(
            W_e2, (long)e * 8388608, WT, 4096, 2048, flag);
        gemm_bt<EPI_EXPERT><<<dim3(16, 32), blk, 0, stream>>>(
            eh, WT, M, 2048, 4096, b_e2, (long)e * 2048, nullptr, 0,
            hacc, probs + e, nullptr, flag);
    }
    // 5b) restore xb (eh clobbered it)
    to_bf16_any<<<dim3(8192), blk, 0, stream>>>(x, xb, 2097152L, flag);
    // 6) h4 snapshot (bf16) into h23
    f32_to_bf16_4<<<dim3(8192), blk, 0, stream>>>(hacc, h23, 2097152L);
    // 7) hacc += h4 @ W_ctx + b_ctx
    transpose_any<<<dim3(32, 32), blk, 0, stream>>>(W_ctx, 0, WT, 2048, 2048, flag);
    gemm_bt<EPI_CTX><<<dim3(16, 32), blk, 0, stream>>>(
        h23, WT, M, 2048, 2048, b_ctx, 0, nullptr, 0, hacc, nullptr, nullptr, flag);
    // 8) h5 = bf16(hacc + conv_b + grouped_conv(h4)) -> hA (ld 2048)
    conv_combine<<<dim3(32, 256, 2), blk, 0, stream>>>(
        h23, hacc, conv_w, conv_b, hA, flag);
    // 9) out = h5 @ W_out + b_out + x
    transpose_any<<<dim3(32, 32), blk, 0, stream>>>(W_out, 0, WT, 2048, 2048, flag);
    gemm_bt<EPI_OUT><<<dim3(16, 32), blk, 0, stream>>>(
        hA, WT, M, 2048, 2048, b_out, 0, d_out, 2048, nullptr, nullptr, xb, flag);
}